// Round 4
// baseline (76.825 us; speedup 1.0000x reference)
//
#include <hip/hip_runtime.h>
#include <math.h>
#include <stdint.h>

#define NB 16
#define S1 128
#define S2 192
#define HH 256   // half hidden
#define PP 4
#define FULLH 512
#define EPSV 1e-8f
#define JCH 16   // q2 rows per LDS chunk in apply

typedef float f32x4 __attribute__((ext_vector_type(4)));
typedef float f32x2 __attribute__((ext_vector_type(2)));
typedef short short8 __attribute__((ext_vector_type(8)));

// ---- workspace layout (float offsets) ----
#define WS_N2    0                 // 6144
#define WS_N2W   6144              // 24576
#define WS_N1    30720             // 4096
#define WS_N1W   34816             // 16384
#define WS_SATT  51200             // [4 jq][4096]
#define WS_MC    67584             // [4 jq][4096][4]
#define WS_ATT   133120            // [4096][192]
#define WS_Q2BF  919552            // uint16 area: [2*NB][12 jt][8 s][64 lane][8 bf16]

__device__ __forceinline__ float dot4(const float4& a, const float4& b) {
    return a.x * b.x + a.y * b.y + a.z * b.z + a.w * b.w;
}

__device__ __forceinline__ uint16_t f2bf(float x) {
    union { float f; uint32_t u; } a;
    a.f = x;
    uint32_t r = a.u + 0x7FFF + ((a.u >> 16) & 1);  // RNE
    return (uint16_t)(r >> 16);
}

__device__ __forceinline__ uint32_t pk2(float a, float b) {
    return (uint32_t)f2bf(a) | ((uint32_t)f2bf(b) << 16);
}

template<int N>
__device__ __forceinline__ void wave_reduce_sum_n(float* v) {
#pragma unroll
    for (int m = 1; m < 64; m <<= 1) {
#pragma unroll
        for (int i = 0; i < N; i++) v[i] += __shfl_xor(v[i], m, 64);
    }
}

// One wave per row: q2 rows (2*NB*S2) then q1 rows (2*NB*S1).
__global__ __launch_bounds__(256) void norms_kernel(const float* __restrict__ q1,
                                                    const float* __restrict__ q2,
                                                    const float* __restrict__ W,
                                                    float* __restrict__ ws) {
    const int NQ2 = 2 * NB * S2;   // 6144
    const int NQ1 = 2 * NB * S1;   // 4096
    int gwid = (int)((blockIdx.x * blockDim.x + threadIdx.x) >> 6);
    int lane = threadIdx.x & 63;
    if (gwid >= NQ2 + NQ1) return;

    const float* row;
    int d;
    float* nout;
    float* nwout;
    bool isq2 = gwid < NQ2;
    int b_ = 0, j_ = 0;
    if (isq2) {
        d = gwid / (NB * S2);
        int rem = gwid - d * (NB * S2);
        b_ = rem / S2;
        j_ = rem - b_ * S2;
        row = q2 + ((size_t)(b_ * S2 + j_)) * FULLH + d * HH;
        nout = ws + WS_N2 + gwid;
        nwout = ws + WS_N2W + (size_t)gwid * PP;
    } else {
        int idx = gwid - NQ2;
        d = idx >> 11;
        int b = (idx >> 7) & 15;
        int i = idx & 127;
        row = q1 + ((size_t)(b * S1 + i)) * FULLH + d * HH;
        nout = ws + WS_N1 + idx;
        nwout = ws + WS_N1W + (size_t)idx * PP;
    }

    int h0 = lane * 4;
    float4 v = *reinterpret_cast<const float4*>(row + h0);
    const float* wmax = W + (size_t)(2 + d) * PP * HH;

    float s[5];
    s[0] = dot4(v, v);
#pragma unroll
    for (int p = 0; p < PP; p++) {
        float4 wv = *reinterpret_cast<const float4*>(wmax + p * HH + h0);
        float4 t;
        t.x = v.x * wv.x; t.y = v.y * wv.y; t.z = v.z * wv.z; t.w = v.w * wv.w;
        s[1 + p] = dot4(t, t);
    }
    wave_reduce_sum_n<5>(s);
    if (lane == 0) {
        nout[0] = sqrtf(s[0]);
#pragma unroll
        for (int p = 0; p < PP; p++) nwout[p] = sqrtf(s[1 + p]);
    }

    if (isq2) {
        uint16_t* q2bf = (uint16_t*)(ws + WS_Q2BF);
        size_t bdbase = (size_t)(d * NB + b_) * (S2 * HH);
        int jt = j_ >> 4, jcol = j_ & 15;
        int sg = lane >> 3;
        int khalf = (lane >> 1) & 3;
        int elo = (lane & 1) * 4;
        size_t off = bdbase + ((size_t)(jt * 8 + sg) * 64 + (khalf << 4) + jcol) * 8 + elo;
        uint2 pk;
        pk.x = pk2(v.x, v.y);
        pk.y = pk2(v.z, v.w);
        *reinterpret_cast<uint2*>(q2bf + off) = pk;
    }
}

// MFMA S-phase: 1 wave per block; block = (d, b, itile of 16 rows, jquarter of 48 cols).
__global__ __launch_bounds__(64) void s_mfma_kernel(const float* __restrict__ q1,
                                                    const float* __restrict__ W,
                                                    float* __restrict__ ws) {
    __shared__ short lA[5 * 2 * 64 * 8];
    __shared__ short lB[6 * 64 * 8];

    int bid = blockIdx.x;
    int jq = bid & 3;
    int itile = (bid >> 2) & 7;
    int b = (bid >> 5) & 15;
    int d = bid >> 9;
    int t = threadIdx.x;

    const uint16_t* q2bf = (const uint16_t*)(ws + WS_Q2BF) + (size_t)(d * NB + b) * (S2 * HH);

    f32x4 acc[5][3];
#pragma unroll
    for (int v = 0; v < 5; v++)
#pragma unroll
        for (int jt_i = 0; jt_i < 3; jt_i++) acc[v][jt_i] = (f32x4){0.f, 0.f, 0.f, 0.f};

    int ar = t >> 2;
    int ak0 = (t & 3) << 4;
    int a_sloc = ak0 >> 5;
    int a_kh = (ak0 >> 3) & 3;
    const float* q1row = q1 + ((size_t)(b * S1 + itile * 16 + ar)) * FULLH + d * HH;

    for (int kc = 0; kc < 4; kc++) {
#pragma unroll
        for (int ci = 0; ci < 6; ci++) {
            int jt = jq * 3 + (ci >> 1);
            int sg = kc * 2 + (ci & 1);
            uint4 src = *reinterpret_cast<const uint4*>(
                q2bf + ((size_t)(jt * 8 + sg) * 64 + t) * 8);
            *reinterpret_cast<uint4*>(&lB[(ci * 64 + t) * 8]) = src;
        }
        {
            int kg = kc * 64 + ak0;
            float4 x0 = *reinterpret_cast<const float4*>(q1row + kg);
            float4 x1 = *reinterpret_cast<const float4*>(q1row + kg + 4);
            float4 x2 = *reinterpret_cast<const float4*>(q1row + kg + 8);
            float4 x3 = *reinterpret_cast<const float4*>(q1row + kg + 12);
#pragma unroll
            for (int v = 0; v < 5; v++) {
                float4 y0 = x0, y1 = x1, y2 = x2, y3 = x3;
                if (v > 0) {
                    const float* wrow = W + ((size_t)((2 + d) * PP + (v - 1))) * HH + kg;
                    float4 w0 = *reinterpret_cast<const float4*>(wrow);
                    float4 w1 = *reinterpret_cast<const float4*>(wrow + 4);
                    float4 w2 = *reinterpret_cast<const float4*>(wrow + 8);
                    float4 w3 = *reinterpret_cast<const float4*>(wrow + 12);
                    y0.x *= w0.x * w0.x; y0.y *= w0.y * w0.y; y0.z *= w0.z * w0.z; y0.w *= w0.w * w0.w;
                    y1.x *= w1.x * w1.x; y1.y *= w1.y * w1.y; y1.z *= w1.z * w1.z; y1.w *= w1.w * w1.w;
                    y2.x *= w2.x * w2.x; y2.y *= w2.y * w2.y; y2.z *= w2.z * w2.z; y2.w *= w2.w * w2.w;
                    y3.x *= w3.x * w3.x; y3.y *= w3.y * w3.y; y3.z *= w3.z * w3.z; y3.w *= w3.w * w3.w;
                }
                uint4 c0, c1;
                c0.x = pk2(y0.x, y0.y); c0.y = pk2(y0.z, y0.w);
                c0.z = pk2(y1.x, y1.y); c0.w = pk2(y1.z, y1.w);
                c1.x = pk2(y2.x, y2.y); c1.y = pk2(y2.z, y2.w);
                c1.z = pk2(y3.x, y3.y); c1.w = pk2(y3.z, y3.w);
                int base = ((v * 2 + a_sloc) * 64 + (a_kh << 4) + ar) * 8;
                *reinterpret_cast<uint4*>(&lA[base]) = c0;
                *reinterpret_cast<uint4*>(&lA[base + 128]) = c1;
            }
        }
        __syncthreads();
#pragma unroll
        for (int sl = 0; sl < 2; sl++) {
            short8 a[5];
#pragma unroll
            for (int v = 0; v < 5; v++)
                a[v] = *reinterpret_cast<const short8*>(&lA[((v * 2 + sl) * 64 + t) * 8]);
#pragma unroll
            for (int jt_i = 0; jt_i < 3; jt_i++) {
                short8 bf = *reinterpret_cast<const short8*>(&lB[((jt_i * 2 + sl) * 64 + t) * 8]);
#pragma unroll
                for (int v = 0; v < 5; v++)
                    acc[v][jt_i] = __builtin_amdgcn_mfma_f32_16x16x32_bf16(a[v], bf, acc[v][jt_i], 0, 0, 0);
            }
        }
        __syncthreads();
    }

    int lhi = t >> 4;
    int lcol = t & 15;
    int nbase = d * (NB * S2) + b * S2;
    int q1b = d * (NB * S1) + b * S1 + itile * 16 + lhi * 4;

    float n1[4], n1wc[4][4];
#pragma unroll
    for (int rr = 0; rr < 4; rr++) {
        n1[rr] = ws[WS_N1 + q1b + rr];
#pragma unroll
        for (int p = 0; p < 4; p++)
            n1wc[rr][p] = fmaxf(ws[WS_N1W + (size_t)(q1b + rr) * 4 + p], EPSV);
    }

    float satt_acc[4] = {0.f, 0.f, 0.f, 0.f};
    float mc_acc[4][4];
#pragma unroll
    for (int p = 0; p < 4; p++)
#pragma unroll
        for (int rr = 0; rr < 4; rr++) mc_acc[p][rr] = -INFINITY;

#pragma unroll
    for (int jt_i = 0; jt_i < 3; jt_i++) {
        int j = (jq * 3 + jt_i) * 16 + lcol;
        float n2 = ws[WS_N2 + nbase + j];
#pragma unroll
        for (int rr = 0; rr < 4; rr++) {
            float den = n1[rr] * n2;
            float att = acc[0][jt_i][rr] / (den > EPSV ? den : EPSV);
            ws[WS_ATT + (size_t)(q1b + rr) * S2 + j] = att;
            satt_acc[rr] += att;
        }
#pragma unroll
        for (int p = 0; p < 4; p++) {
            float n2wv = fmaxf(ws[WS_N2W + (size_t)(nbase + j) * 4 + p], EPSV);
#pragma unroll
            for (int rr = 0; rr < 4; rr++) {
                float cosv = acc[p + 1][jt_i][rr] / (n1wc[rr][p] * n2wv);
                mc_acc[p][rr] = fmaxf(mc_acc[p][rr], cosv);
            }
        }
    }

#pragma unroll
    for (int m = 1; m < 16; m <<= 1) {
#pragma unroll
        for (int rr = 0; rr < 4; rr++) satt_acc[rr] += __shfl_xor(satt_acc[rr], m, 64);
#pragma unroll
        for (int p = 0; p < 4; p++)
#pragma unroll
            for (int rr = 0; rr < 4; rr++)
                mc_acc[p][rr] = fmaxf(mc_acc[p][rr], __shfl_xor(mc_acc[p][rr], m, 64));
    }
    if (lcol == 0) {
#pragma unroll
        for (int rr = 0; rr < 4; rr++) {
            ws[WS_SATT + jq * 4096 + q1b + rr] = satt_acc[rr];
#pragma unroll
            for (int p = 0; p < 4; p++)
                ws[WS_MC + (size_t)(jq * 4096 + q1b + rr) * 4 + p] = mc_acc[p][rr];
        }
    }
}

// Apply v2: block per (d, b, itile of 16 i's), 256 thr = 4 waves, wave owns 4 i's.
// q2 staged chunk-wise (16 rows) into dbuf LDS via global_load_lds; att
// pre-staged transposed [192][16]; inner loop has zero global loads.
__global__ __launch_bounds__(256) void apply_kernel(const float* __restrict__ q1,
                                                    const float* __restrict__ q2,
                                                    const float* __restrict__ W,
                                                    const float* __restrict__ ws,
                                                    float* __restrict__ out) {
    __shared__ float q2s[2][JCH][HH];   // 32 KB
    __shared__ float atts[S2][16];      // 12 KB, [j][ii]

    int bid = blockIdx.x;
    int itile = bid & 7;
    int b = (bid >> 3) & 15;
    int d = bid >> 7;
    int tid = threadIdx.x;
    int w = tid >> 6;
    int lane = tid & 63;
    int h0 = lane * 4;

    int i0 = itile * 16;
    int q1base = d * (NB * S1) + b * S1 + i0;   // ws row index for block's i0
    const float* q2b = q2 + (size_t)b * S2 * FULLH + d * HH;

    // stage att transposed (linear LDS writes, conflict-free)
    for (int idx = tid; idx < S2 * 16; idx += 256) {
        int j = idx >> 4;
        int ii = idx & 15;
        atts[j][ii] = ws[WS_ATT + (size_t)(q1base + ii) * S2 + j];
    }

    // stage chunk 0 (wave w stages rows w*4..w*4+3)
#pragma unroll
    for (int r = 0; r < 4; r++) {
        int jr = w * 4 + r;
        const float* src = q2b + (size_t)jr * FULLH + h0;
        __builtin_amdgcn_global_load_lds(
            (const __attribute__((address_space(1))) unsigned int*)src,
            (__attribute__((address_space(3))) unsigned int*)&q2s[0][jr][0],
            16, 0, 0);
    }
    __syncthreads();

    f32x2 mlo[4], mhi[4], xlo[4], xhi[4];
#pragma unroll
    for (int ii = 0; ii < 4; ii++) {
        mlo[ii] = (f32x2){0.f, 0.f};
        mhi[ii] = (f32x2){0.f, 0.f};
        xlo[ii] = (f32x2){-INFINITY, -INFINITY};
        xhi[ii] = (f32x2){-INFINITY, -INFINITY};
    }

    for (int c = 0; c < 12; c++) {
        int buf = c & 1;
        if (c < 11) {
#pragma unroll
            for (int r = 0; r < 4; r++) {
                int jr = w * 4 + r;
                const float* src = q2b + (size_t)((c + 1) * JCH + jr) * FULLH + h0;
                __builtin_amdgcn_global_load_lds(
                    (const __attribute__((address_space(1))) unsigned int*)src,
                    (__attribute__((address_space(3))) unsigned int*)&q2s[buf ^ 1][jr][0],
                    16, 0, 0);
            }
        }
#pragma unroll
        for (int jr = 0; jr < JCH; jr++) {
            float4 qv = *reinterpret_cast<const float4*>(&q2s[buf][jr][h0]);
            float4 a4 = *reinterpret_cast<const float4*>(&atts[c * JCH + jr][w * 4]);
            f32x2 qlo = (f32x2){qv.x, qv.y};
            f32x2 qhi = (f32x2){qv.z, qv.w};
            float av[4] = {a4.x, a4.y, a4.z, a4.w};
#pragma unroll
            for (int ii = 0; ii < 4; ii++) {
                f32x2 a2 = (f32x2){av[ii], av[ii]};
                mlo[ii] = __builtin_elementwise_fma(a2, qlo, mlo[ii]);
                mhi[ii] = __builtin_elementwise_fma(a2, qhi, mhi[ii]);
                xlo[ii] = __builtin_elementwise_max(xlo[ii], a2 * qlo);
                xhi[ii] = __builtin_elementwise_max(xhi[ii], a2 * qhi);
            }
        }
        __syncthreads();
    }

    // epilogue: per ii, full set of 12 cosines + maxpool merge
    float4 rv = *reinterpret_cast<const float4*>(
        q2b + (d == 0 ? (size_t)(S2 - 1) * FULLH : (size_t)0) + h0);

#pragma unroll
    for (int ii = 0; ii < 4; ii++) {
        int iglob = i0 + w * 4 + ii;                 // i within batch
        int q1idx = q1base + w * 4 + ii;             // ws row index
        size_t obase = ((size_t)(b * S1 + iglob)) * 32;

        float satt = ws[WS_SATT + 0 * 4096 + q1idx] + ws[WS_SATT + 1 * 4096 + q1idx] +
                     ws[WS_SATT + 2 * 4096 + q1idx] + ws[WS_SATT + 3 * 4096 + q1idx];
        float sden = satt > EPSV ? satt : EPSV;

        if (lane < 4) {
            float m = -INFINITY;
#pragma unroll
            for (int jq = 0; jq < 4; jq++)
                m = fmaxf(m, ws[WS_MC + (size_t)(jq * 4096 + q1idx) * 4 + lane]);
            out[obase + 8 + 4 * d + lane] = m;
        }

        float4 q1v = *reinterpret_cast<const float4*>(
            q1 + ((size_t)(b * S1 + iglob)) * FULLH + d * HH + h0);
        float4 mean;
        mean.x = mlo[ii].x / sden; mean.y = mlo[ii].y / sden;
        mean.z = mhi[ii].x / sden; mean.w = mhi[ii].y / sden;
        float4 mx;
        mx.x = xlo[ii].x; mx.y = xlo[ii].y; mx.z = xhi[ii].x; mx.w = xhi[ii].y;

        float s[36];
#pragma unroll
        for (int m = 0; m < 3; m++) {
            float4 xv = (m == 0) ? rv : (m == 1) ? mean : mx;
            int wb = (m == 0) ? d : (m == 1) ? 4 + d : 6 + d;
#pragma unroll
            for (int p = 0; p < 4; p++) {
                float4 wv = *reinterpret_cast<const float4*>(W + ((size_t)wb * PP + p) * HH + h0);
                float4 w2;
                w2.x = wv.x * wv.x; w2.y = wv.y * wv.y;
                w2.z = wv.z * wv.z; w2.w = wv.w * wv.w;
                float4 tq, u;
                tq.x = q1v.x * w2.x; tq.y = q1v.y * w2.y;
                tq.z = q1v.z * w2.z; tq.w = q1v.w * w2.w;
                u.x = xv.x * w2.x; u.y = xv.y * w2.y;
                u.z = xv.z * w2.z; u.w = xv.w * w2.w;
                int base = (m * 4 + p) * 3;
                s[base + 0] = tq.x * xv.x + tq.y * xv.y + tq.z * xv.z + tq.w * xv.w;
                s[base + 1] = tq.x * q1v.x + tq.y * q1v.y + tq.z * q1v.z + tq.w * q1v.w;
                s[base + 2] = u.x * xv.x + u.y * xv.y + u.z * xv.z + u.w * xv.w;
            }
        }
        wave_reduce_sum_n<36>(s);
        if (lane == 0) {
            const int obm[3] = {0, 16, 24};
#pragma unroll
            for (int m = 0; m < 3; m++) {
#pragma unroll
                for (int p = 0; p < 4; p++) {
                    int base = (m * 4 + p) * 3;
                    out[obase + obm[m] + 4 * d + p] =
                        s[base] / (fmaxf(sqrtf(s[base + 1]), EPSV) *
                                   fmaxf(sqrtf(s[base + 2]), EPSV));
                }
            }
        }
    }
}

extern "C" void kernel_launch(void* const* d_in, const int* in_sizes, int n_in,
                              void* d_out, int out_size, void* d_ws, size_t ws_size,
                              hipStream_t stream) {
    const float* q1 = (const float*)d_in[0];
    const float* q2 = (const float*)d_in[1];
    const float* W = (const float*)d_in[2];
    float* out = (float*)d_out;
    float* ws = (float*)d_ws;

    int nrows = 2 * NB * S2 + 2 * NB * S1;             // 10240 waves
    int nblocks_norm = (nrows * 64 + 255) / 256;       // 2560
    norms_kernel<<<dim3(nblocks_norm), dim3(256), 0, stream>>>(q1, q2, W, ws);

    s_mfma_kernel<<<dim3(2 * NB * 8 * 4), dim3(64), 0, stream>>>(q1, W, ws);

    apply_kernel<<<dim3(2 * NB * 8), dim3(256), 0, stream>>>(q1, q2, W, ws, out);
}

// Round 5
// 68.759 us; speedup vs baseline: 1.1173x; 1.1173x over previous
//
#include <hip/hip_runtime.h>
#include <math.h>
#include <stdint.h>

#define NB 16
#define S1 128
#define S2 192
#define HH 256   // half hidden
#define PP 4
#define FULLH 512
#define EPSV 1e-8f

typedef float f32x4 __attribute__((ext_vector_type(4)));
typedef float f32x2 __attribute__((ext_vector_type(2)));
typedef short short8 __attribute__((ext_vector_type(8)));

// ---- workspace layout (float offsets) ----
#define WS_N2    0                 // 6144
#define WS_N2W   6144              // 24576
#define WS_N1    30720             // 4096
#define WS_N1W   34816             // 16384  (maxpool bank W[2+d])
#define WS_SATT  51200             // [4 jq][4096]
#define WS_MC    67584             // [4 jq][4096][4]
#define WS_ATT   133120            // transposed: [2NB db][192 j][128 i]
#define WS_Q2BF  919552            // uint16 area: [2*NB][12 jt][8 s][64 lane][8 bf16] (786432 floats)
#define WS_N1X   1705984           // [4096][12]: q1 norms for banks W[d],W[4+d],W[6+d]
#define WS_RVN   1755136           // [2NB db][4]: rv norms with W[d]

__device__ __forceinline__ float dot4(const float4& a, const float4& b) {
    return a.x * b.x + a.y * b.y + a.z * b.z + a.w * b.w;
}

__device__ __forceinline__ float vdot4(const f32x4& a, const f32x4& b) {
    return a.x * b.x + a.y * b.y + a.z * b.z + a.w * b.w;
}

__device__ __forceinline__ uint16_t f2bf(float x) {
    union { float f; uint32_t u; } a;
    a.f = x;
    uint32_t r = a.u + 0x7FFF + ((a.u >> 16) & 1);  // RNE
    return (uint16_t)(r >> 16);
}

__device__ __forceinline__ uint32_t pk2(float a, float b) {
    return (uint32_t)f2bf(a) | ((uint32_t)f2bf(b) << 16);
}

template<int N>
__device__ __forceinline__ void wave_reduce_sum_n(float* v) {
#pragma unroll
    for (int m = 1; m < 64; m <<= 1) {
#pragma unroll
        for (int i = 0; i < N; i++) v[i] += __shfl_xor(v[i], m, 64);
    }
}

// One wave per row: q2 rows (2*NB*S2) then q1 rows (2*NB*S1).
// q1 rows: plain + 16 weighted norms (banks W[2+d], W[d], W[4+d], W[6+d]).
// q2 rows: plain + 4 weighted (W[2+d]) + bf16 frag-major convert; rv rows
// additionally get W[d]-weighted norms (-> WS_RVN).
__global__ __launch_bounds__(256) void norms_kernel(const float* __restrict__ q1,
                                                    const float* __restrict__ q2,
                                                    const float* __restrict__ W,
                                                    float* __restrict__ ws) {
    const int NQ2 = 2 * NB * S2;   // 6144
    const int NQ1 = 2 * NB * S1;   // 4096
    int gwid = (int)((blockIdx.x * blockDim.x + threadIdx.x) >> 6);
    int lane = threadIdx.x & 63;
    if (gwid >= NQ2 + NQ1) return;

    int h0 = lane * 4;

    if (gwid < NQ2) {
        int d = gwid / (NB * S2);
        int rem = gwid - d * (NB * S2);
        int b_ = rem / S2;
        int j_ = rem - b_ * S2;
        const float* row = q2 + ((size_t)(b_ * S2 + j_)) * FULLH + d * HH;
        float4 v = *reinterpret_cast<const float4*>(row + h0);
        const float* wmax = W + (size_t)(2 + d) * PP * HH;

        float s[5];
        s[0] = dot4(v, v);
#pragma unroll
        for (int p = 0; p < PP; p++) {
            float4 wv = *reinterpret_cast<const float4*>(wmax + p * HH + h0);
            float4 t;
            t.x = v.x * wv.x; t.y = v.y * wv.y; t.z = v.z * wv.z; t.w = v.w * wv.w;
            s[1 + p] = dot4(t, t);
        }
        wave_reduce_sum_n<5>(s);
        if (lane == 0) {
            ws[WS_N2 + gwid] = sqrtf(s[0]);
#pragma unroll
            for (int p = 0; p < PP; p++)
                ws[WS_N2W + (size_t)gwid * PP + p] = sqrtf(s[1 + p]);
        }

        // rv rows: extra norms with W[d]
        if ((d == 0 && j_ == S2 - 1) || (d == 1 && j_ == 0)) {
            float e[4];
#pragma unroll
            for (int p = 0; p < PP; p++) {
                float4 wv = *reinterpret_cast<const float4*>(W + ((size_t)d * PP + p) * HH + h0);
                float4 t;
                t.x = v.x * wv.x; t.y = v.y * wv.y; t.z = v.z * wv.z; t.w = v.w * wv.w;
                e[p] = dot4(t, t);
            }
            wave_reduce_sum_n<4>(e);
            if (lane == 0) {
#pragma unroll
                for (int p = 0; p < PP; p++)
                    ws[WS_RVN + (d * NB + b_) * 4 + p] = sqrtf(e[p]);
            }
        }

        // bf16 frag-major convert
        uint16_t* q2bf = (uint16_t*)(ws + WS_Q2BF);
        size_t bdbase = (size_t)(d * NB + b_) * (S2 * HH);
        int jt = j_ >> 4, jcol = j_ & 15;
        int sg = lane >> 3;
        int khalf = (lane >> 1) & 3;
        int elo = (lane & 1) * 4;
        size_t off = bdbase + ((size_t)(jt * 8 + sg) * 64 + (khalf << 4) + jcol) * 8 + elo;
        uint2 pk;
        pk.x = pk2(v.x, v.y);
        pk.y = pk2(v.z, v.w);
        *reinterpret_cast<uint2*>(q2bf + off) = pk;
    } else {
        int idx = gwid - NQ2;
        int d = idx >> 11;
        int b = (idx >> 7) & 15;
        int i = idx & 127;
        const float* row = q1 + ((size_t)(b * S1 + i)) * FULLH + d * HH;
        float4 v = *reinterpret_cast<const float4*>(row + h0);

        int banks[4] = {2 + d, d, 4 + d, 6 + d};
        float s[17];
        s[0] = dot4(v, v);
#pragma unroll
        for (int t = 0; t < 4; t++) {
#pragma unroll
            for (int p = 0; p < PP; p++) {
                float4 wv = *reinterpret_cast<const float4*>(
                    W + ((size_t)banks[t] * PP + p) * HH + h0);
                float4 tv;
                tv.x = v.x * wv.x; tv.y = v.y * wv.y;
                tv.z = v.z * wv.z; tv.w = v.w * wv.w;
                s[1 + t * 4 + p] = dot4(tv, tv);
            }
        }
        wave_reduce_sum_n<17>(s);
        if (lane == 0) {
            ws[WS_N1 + idx] = sqrtf(s[0]);
#pragma unroll
            for (int p = 0; p < PP; p++)
                ws[WS_N1W + (size_t)idx * PP + p] = sqrtf(s[1 + p]);
#pragma unroll
            for (int t = 0; t < 3; t++)
#pragma unroll
                for (int p = 0; p < PP; p++)
                    ws[WS_N1X + (size_t)idx * 12 + t * 4 + p] = sqrtf(s[5 + t * 4 + p]);
        }
    }
}

// MFMA S-phase: 1 wave per block; block = (d, b, itile of 16 rows, jquarter of 48 cols).
__global__ __launch_bounds__(64) void s_mfma_kernel(const float* __restrict__ q1,
                                                    const float* __restrict__ W,
                                                    float* __restrict__ ws) {
    __shared__ short lA[5 * 2 * 64 * 8];
    __shared__ short lB[6 * 64 * 8];

    int bid = blockIdx.x;
    int jq = bid & 3;
    int itile = (bid >> 2) & 7;
    int b = (bid >> 5) & 15;
    int d = bid >> 9;
    int t = threadIdx.x;

    const uint16_t* q2bf = (const uint16_t*)(ws + WS_Q2BF) + (size_t)(d * NB + b) * (S2 * HH);

    f32x4 acc[5][3];
#pragma unroll
    for (int v = 0; v < 5; v++)
#pragma unroll
        for (int jt_i = 0; jt_i < 3; jt_i++) acc[v][jt_i] = (f32x4){0.f, 0.f, 0.f, 0.f};

    int ar = t >> 2;
    int ak0 = (t & 3) << 4;
    int a_sloc = ak0 >> 5;
    int a_kh = (ak0 >> 3) & 3;
    const float* q1row = q1 + ((size_t)(b * S1 + itile * 16 + ar)) * FULLH + d * HH;

    for (int kc = 0; kc < 4; kc++) {
#pragma unroll
        for (int ci = 0; ci < 6; ci++) {
            int jt = jq * 3 + (ci >> 1);
            int sg = kc * 2 + (ci & 1);
            uint4 src = *reinterpret_cast<const uint4*>(
                q2bf + ((size_t)(jt * 8 + sg) * 64 + t) * 8);
            *reinterpret_cast<uint4*>(&lB[(ci * 64 + t) * 8]) = src;
        }
        {
            int kg = kc * 64 + ak0;
            float4 x0 = *reinterpret_cast<const float4*>(q1row + kg);
            float4 x1 = *reinterpret_cast<const float4*>(q1row + kg + 4);
            float4 x2 = *reinterpret_cast<const float4*>(q1row + kg + 8);
            float4 x3 = *reinterpret_cast<const float4*>(q1row + kg + 12);
#pragma unroll
            for (int v = 0; v < 5; v++) {
                float4 y0 = x0, y1 = x1, y2 = x2, y3 = x3;
                if (v > 0) {
                    const float* wrow = W + ((size_t)((2 + d) * PP + (v - 1))) * HH + kg;
                    float4 w0 = *reinterpret_cast<const float4*>(wrow);
                    float4 w1 = *reinterpret_cast<const float4*>(wrow + 4);
                    float4 w2 = *reinterpret_cast<const float4*>(wrow + 8);
                    float4 w3 = *reinterpret_cast<const float4*>(wrow + 12);
                    y0.x *= w0.x * w0.x; y0.y *= w0.y * w0.y; y0.z *= w0.z * w0.z; y0.w *= w0.w * w0.w;
                    y1.x *= w1.x * w1.x; y1.y *= w1.y * w1.y; y1.z *= w1.z * w1.z; y1.w *= w1.w * w1.w;
                    y2.x *= w2.x * w2.x; y2.y *= w2.y * w2.y; y2.z *= w2.z * w2.z; y2.w *= w2.w * w2.w;
                    y3.x *= w3.x * w3.x; y3.y *= w3.y * w3.y; y3.z *= w3.z * w3.z; y3.w *= w3.w * w3.w;
                }
                uint4 c0, c1;
                c0.x = pk2(y0.x, y0.y); c0.y = pk2(y0.z, y0.w);
                c0.z = pk2(y1.x, y1.y); c0.w = pk2(y1.z, y1.w);
                c1.x = pk2(y2.x, y2.y); c1.y = pk2(y2.z, y2.w);
                c1.z = pk2(y3.x, y3.y); c1.w = pk2(y3.z, y3.w);
                int base = ((v * 2 + a_sloc) * 64 + (a_kh << 4) + ar) * 8;
                *reinterpret_cast<uint4*>(&lA[base]) = c0;
                *reinterpret_cast<uint4*>(&lA[base + 128]) = c1;
            }
        }
        __syncthreads();
#pragma unroll
        for (int sl = 0; sl < 2; sl++) {
            short8 a[5];
#pragma unroll
            for (int v = 0; v < 5; v++)
                a[v] = *reinterpret_cast<const short8*>(&lA[((v * 2 + sl) * 64 + t) * 8]);
#pragma unroll
            for (int jt_i = 0; jt_i < 3; jt_i++) {
                short8 bf = *reinterpret_cast<const short8*>(&lB[((jt_i * 2 + sl) * 64 + t) * 8]);
#pragma unroll
                for (int v = 0; v < 5; v++)
                    acc[v][jt_i] = __builtin_amdgcn_mfma_f32_16x16x32_bf16(a[v], bf, acc[v][jt_i], 0, 0, 0);
            }
        }
        __syncthreads();
    }

    int lhi = t >> 4;
    int lcol = t & 15;
    int nbase = d * (NB * S2) + b * S2;
    int q1b = d * (NB * S1) + b * S1 + itile * 16 + lhi * 4;
    int iloc = itile * 16 + lhi * 4;
    float* attT = ws + WS_ATT + (size_t)(d * NB + b) * S2 * S1;

    float n1[4], n1wc[4][4];
#pragma unroll
    for (int rr = 0; rr < 4; rr++) {
        n1[rr] = ws[WS_N1 + q1b + rr];
#pragma unroll
        for (int p = 0; p < 4; p++)
            n1wc[rr][p] = fmaxf(ws[WS_N1W + (size_t)(q1b + rr) * 4 + p], EPSV);
    }

    float satt_acc[4] = {0.f, 0.f, 0.f, 0.f};
    float mc_acc[4][4];
#pragma unroll
    for (int p = 0; p < 4; p++)
#pragma unroll
        for (int rr = 0; rr < 4; rr++) mc_acc[p][rr] = -INFINITY;

#pragma unroll
    for (int jt_i = 0; jt_i < 3; jt_i++) {
        int j = (jq * 3 + jt_i) * 16 + lcol;
        float n2 = ws[WS_N2 + nbase + j];
        float4 av;
        float avv[4];
#pragma unroll
        for (int rr = 0; rr < 4; rr++) {
            float den = n1[rr] * n2;
            avv[rr] = acc[0][jt_i][rr] / (den > EPSV ? den : EPSV);
            satt_acc[rr] += avv[rr];
        }
        av.x = avv[0]; av.y = avv[1]; av.z = avv[2]; av.w = avv[3];
        *reinterpret_cast<float4*>(&attT[(size_t)j * S1 + iloc]) = av;  // transposed
#pragma unroll
        for (int p = 0; p < 4; p++) {
            float n2wv = fmaxf(ws[WS_N2W + (size_t)(nbase + j) * 4 + p], EPSV);
#pragma unroll
            for (int rr = 0; rr < 4; rr++) {
                float cosv = acc[p + 1][jt_i][rr] / (n1wc[rr][p] * n2wv);
                mc_acc[p][rr] = fmaxf(mc_acc[p][rr], cosv);
            }
        }
    }

#pragma unroll
    for (int m = 1; m < 16; m <<= 1) {
#pragma unroll
        for (int rr = 0; rr < 4; rr++) satt_acc[rr] += __shfl_xor(satt_acc[rr], m, 64);
#pragma unroll
        for (int p = 0; p < 4; p++)
#pragma unroll
            for (int rr = 0; rr < 4; rr++)
                mc_acc[p][rr] = fmaxf(mc_acc[p][rr], __shfl_xor(mc_acc[p][rr], m, 64));
    }
    if (lcol == 0) {
#pragma unroll
        for (int rr = 0; rr < 4; rr++) {
            ws[WS_SATT + jq * 4096 + q1b + rr] = satt_acc[rr];
#pragma unroll
            for (int p = 0; p < 4; p++)
                ws[WS_MC + (size_t)(jq * 4096 + q1b + rr) * 4 + p] = mc_acc[p][rr];
        }
    }
}

// Apply v3: barrier-free streaming. Wave = (d, b, 2 i's, full 256 h).
// 512 blocks x 4 waves; the 4 waves of a block share (d,b) -> L1 reuse.
// XCD-swizzle: all 16 blocks of a (d,b) land on one XCD.
__global__ __launch_bounds__(256) void apply_kernel(const float* __restrict__ q1,
                                                    const float* __restrict__ q2,
                                                    const float* __restrict__ W,
                                                    const float* __restrict__ ws,
                                                    float* __restrict__ out) {
    int bid = blockIdx.x;
    int xcd = bid & 7;
    int sg = bid >> 3;               // 0..63
    int db = xcd + 8 * (sg & 3);     // 0..31, fixed xcd per db
    int quad = sg >> 2;              // 0..15
    int d = db >> 4;
    int b = db & 15;

    int tid = threadIdx.x;
    int w = tid >> 6;
    int lane = tid & 63;
    int h0 = lane * 4;

    int i0 = __builtin_amdgcn_readfirstlane(quad * 8 + w * 2);  // 2 i's per wave

    const float* q2b = q2 + (size_t)b * S2 * FULLH + d * HH;
    const float* attT = ws + WS_ATT + (size_t)db * S2 * S1 + i0;

    f32x4 macc0 = (f32x4){0.f, 0.f, 0.f, 0.f};
    f32x4 macc1 = (f32x4){0.f, 0.f, 0.f, 0.f};
    f32x4 mx0 = (f32x4){-INFINITY, -INFINITY, -INFINITY, -INFINITY};
    f32x4 mx1 = (f32x4){-INFINITY, -INFINITY, -INFINITY, -INFINITY};

#pragma unroll 4
    for (int j = 0; j < S2; j++) {
        f32x4 qv = *reinterpret_cast<const f32x4*>(q2b + (size_t)j * FULLH + h0);
        f32x2 a2 = *reinterpret_cast<const f32x2*>(attT + (size_t)j * S1);
        f32x4 a0 = (f32x4){a2.x, a2.x, a2.x, a2.x};
        f32x4 a1 = (f32x4){a2.y, a2.y, a2.y, a2.y};
        macc0 = __builtin_elementwise_fma(a0, qv, macc0);
        macc1 = __builtin_elementwise_fma(a1, qv, macc1);
        mx0 = __builtin_elementwise_max(mx0, a0 * qv);
        mx1 = __builtin_elementwise_max(mx1, a1 * qv);
    }

    int q1i0 = d * (NB * S1) + b * S1 + i0;  // ws row index, ii=0

    // satt for both i's
    float satt0 = 0.f, satt1 = 0.f;
#pragma unroll
    for (int jq = 0; jq < 4; jq++) {
        satt0 += ws[WS_SATT + jq * 4096 + q1i0];
        satt1 += ws[WS_SATT + jq * 4096 + q1i0 + 1];
    }
    float sden0 = satt0 > EPSV ? satt0 : EPSV;
    float sden1 = satt1 > EPSV ? satt1 : EPSV;

    // maxpool merge outputs (8 lanes: ii = lane>>2, p = lane&3)
    if (lane < 8) {
        int ii = lane >> 2;
        int p = lane & 3;
        float m = -INFINITY;
#pragma unroll
        for (int jq = 0; jq < 4; jq++)
            m = fmaxf(m, ws[WS_MC + (size_t)(jq * 4096 + q1i0 + ii) * 4 + p]);
        out[((size_t)(b * S1 + i0 + ii)) * 32 + 8 + 4 * d + p] = m;
    }

    f32x4 mean0 = macc0 * (1.0f / sden0);
    f32x4 mean1 = macc1 * (1.0f / sden1);
    f32x4 rv = *reinterpret_cast<const f32x4*>(
        q2b + (d == 0 ? (size_t)(S2 - 1) * FULLH : (size_t)0) + h0);
    f32x4 q1v0 = *reinterpret_cast<const f32x4*>(
        q1 + ((size_t)(b * S1 + i0)) * FULLH + d * HH + h0);
    f32x4 q1v1 = *reinterpret_cast<const f32x4*>(
        q1 + ((size_t)(b * S1 + i0 + 1)) * FULLH + d * HH + h0);

    // per-i products
    f32x4 q1rv0 = q1v0 * rv, q1me0 = q1v0 * mean0, me20 = mean0 * mean0;
    f32x4 q1mx0 = q1v0 * mx0, mx20 = mx0 * mx0;
    f32x4 q1rv1 = q1v1 * rv, q1me1 = q1v1 * mean1, me21 = mean1 * mean1;
    f32x4 q1mx1 = q1v1 * mx1, mx21 = mx1 * mx1;

    // s[ii*20 + p*5 + {0:full-num, 1:att-num, 2:mean2, 3:max-num, 4:mx2}]
    float s[40];
#pragma unroll
    for (int p = 0; p < 4; p++) {
        f32x4 wf = *reinterpret_cast<const f32x4*>(W + ((size_t)d * PP + p) * HH + h0);
        f32x4 wa = *reinterpret_cast<const f32x4*>(W + ((size_t)(4 + d) * PP + p) * HH + h0);
        f32x4 wm = *reinterpret_cast<const f32x4*>(W + ((size_t)(6 + d) * PP + p) * HH + h0);
        f32x4 w2f = wf * wf, w2a = wa * wa, w2m = wm * wm;
        s[p * 5 + 0] = vdot4(q1rv0, w2f);
        s[p * 5 + 1] = vdot4(q1me0, w2a);
        s[p * 5 + 2] = vdot4(me20, w2a);
        s[p * 5 + 3] = vdot4(q1mx0, w2m);
        s[p * 5 + 4] = vdot4(mx20, w2m);
        s[20 + p * 5 + 0] = vdot4(q1rv1, w2f);
        s[20 + p * 5 + 1] = vdot4(q1me1, w2a);
        s[20 + p * 5 + 2] = vdot4(me21, w2a);
        s[20 + p * 5 + 3] = vdot4(q1mx1, w2m);
        s[20 + p * 5 + 4] = vdot4(mx21, w2m);
    }
    wave_reduce_sum_n<40>(s);

    if (lane == 0) {
#pragma unroll
        for (int ii = 0; ii < 2; ii++) {
            int qi = q1i0 + ii;
            size_t obase = ((size_t)(b * S1 + i0 + ii)) * 32;
            const float* nx = ws + WS_N1X + (size_t)qi * 12;
#pragma unroll
            for (int p = 0; p < 4; p++) {
                float nf = fmaxf(nx[p], EPSV);
                float na = fmaxf(nx[4 + p], EPSV);
                float nm = fmaxf(nx[8 + p], EPSV);
                float rvn = fmaxf(ws[WS_RVN + (d * NB + b) * 4 + p], EPSV);
                const float* sp = s + ii * 20 + p * 5;
                out[obase + 0 + 4 * d + p] = sp[0] / (nf * rvn);
                out[obase + 16 + 4 * d + p] = sp[1] / (na * fmaxf(sqrtf(sp[2]), EPSV));
                out[obase + 24 + 4 * d + p] = sp[3] / (nm * fmaxf(sqrtf(sp[4]), EPSV));
            }
        }
    }
}

extern "C" void kernel_launch(void* const* d_in, const int* in_sizes, int n_in,
                              void* d_out, int out_size, void* d_ws, size_t ws_size,
                              hipStream_t stream) {
    const float* q1 = (const float*)d_in[0];
    const float* q2 = (const float*)d_in[1];
    const float* W = (const float*)d_in[2];
    float* out = (float*)d_out;
    float* ws = (float*)d_ws;

    int nrows = 2 * NB * S2 + 2 * NB * S1;             // 10240 waves
    int nblocks_norm = (nrows * 64 + 255) / 256;       // 2560
    norms_kernel<<<dim3(nblocks_norm), dim3(256), 0, stream>>>(q1, q2, W, ws);

    s_mfma_kernel<<<dim3(2 * NB * 8 * 4), dim3(64), 0, stream>>>(q1, W, ws);

    apply_kernel<<<dim3(512), dim3(256), 0, stream>>>(q1, q2, W, ws, out);
}

// Round 6
// 61.092 us; speedup vs baseline: 1.2575x; 1.1255x over previous
//
#include <hip/hip_runtime.h>
#include <math.h>
#include <stdint.h>

#define NB 16
#define S1 128
#define S2 192
#define HH 256   // half hidden
#define PP 4
#define FULLH 512
#define EPSV 1e-8f

typedef float f32x4 __attribute__((ext_vector_type(4)));
typedef float f32x2 __attribute__((ext_vector_type(2)));
typedef short short8 __attribute__((ext_vector_type(8)));

// ---- workspace layout (float offsets) ----
#define WS_N2    0                 // 6144
#define WS_N2W   6144              // 24576
#define WS_N1    30720             // 4096
#define WS_N1W   34816             // 16384  (maxpool bank W[2+d])
#define WS_SATT  51200             // [4 jq][4096]
#define WS_MC    67584             // [4 jq][4096][4]
#define WS_ATT   133120            // transposed: [2NB db][192 j][128 i]
#define WS_Q2BF  919552            // uint16 area: [2*NB][12 jt][8 s][64 lane][8 bf16] (786432 floats)
#define WS_N1X   1705984           // [4096][12]: q1 norms for banks W[d],W[4+d],W[6+d]
#define WS_RVN   1755136           // [2NB db][4]: rv norms with W[d]

__device__ __forceinline__ float dot4(const float4& a, const float4& b) {
    return a.x * b.x + a.y * b.y + a.z * b.z + a.w * b.w;
}

__device__ __forceinline__ float vdot4(const f32x4& a, const f32x4& b) {
    return a.x * b.x + a.y * b.y + a.z * b.z + a.w * b.w;
}

__device__ __forceinline__ uint16_t f2bf(float x) {
    union { float f; uint32_t u; } a;
    a.f = x;
    uint32_t r = a.u + 0x7FFF + ((a.u >> 16) & 1);  // RNE
    return (uint16_t)(r >> 16);
}

__device__ __forceinline__ uint32_t pk2(float a, float b) {
    return (uint32_t)f2bf(a) | ((uint32_t)f2bf(b) << 16);
}

template<int N>
__device__ __forceinline__ void wave_reduce_sum_n(float* v) {
#pragma unroll
    for (int m = 1; m < 64; m <<= 1) {
#pragma unroll
        for (int i = 0; i < N; i++) v[i] += __shfl_xor(v[i], m, 64);
    }
}

// One wave per row: q2 rows (2*NB*S2) then q1 rows (2*NB*S1).
__global__ __launch_bounds__(256) void norms_kernel(const float* __restrict__ q1,
                                                    const float* __restrict__ q2,
                                                    const float* __restrict__ W,
                                                    float* __restrict__ ws) {
    const int NQ2 = 2 * NB * S2;   // 6144
    const int NQ1 = 2 * NB * S1;   // 4096
    int gwid = (int)((blockIdx.x * blockDim.x + threadIdx.x) >> 6);
    int lane = threadIdx.x & 63;
    if (gwid >= NQ2 + NQ1) return;

    int h0 = lane * 4;

    if (gwid < NQ2) {
        int d = gwid / (NB * S2);
        int rem = gwid - d * (NB * S2);
        int b_ = rem / S2;
        int j_ = rem - b_ * S2;
        const float* row = q2 + ((size_t)(b_ * S2 + j_)) * FULLH + d * HH;
        float4 v = *reinterpret_cast<const float4*>(row + h0);
        const float* wmax = W + (size_t)(2 + d) * PP * HH;

        float s[5];
        s[0] = dot4(v, v);
#pragma unroll
        for (int p = 0; p < PP; p++) {
            float4 wv = *reinterpret_cast<const float4*>(wmax + p * HH + h0);
            float4 t;
            t.x = v.x * wv.x; t.y = v.y * wv.y; t.z = v.z * wv.z; t.w = v.w * wv.w;
            s[1 + p] = dot4(t, t);
        }
        wave_reduce_sum_n<5>(s);
        if (lane == 0) {
            ws[WS_N2 + gwid] = sqrtf(s[0]);
#pragma unroll
            for (int p = 0; p < PP; p++)
                ws[WS_N2W + (size_t)gwid * PP + p] = sqrtf(s[1 + p]);
        }

        // rv rows: extra norms with W[d]
        if ((d == 0 && j_ == S2 - 1) || (d == 1 && j_ == 0)) {
            float e[4];
#pragma unroll
            for (int p = 0; p < PP; p++) {
                float4 wv = *reinterpret_cast<const float4*>(W + ((size_t)d * PP + p) * HH + h0);
                float4 t;
                t.x = v.x * wv.x; t.y = v.y * wv.y; t.z = v.z * wv.z; t.w = v.w * wv.w;
                e[p] = dot4(t, t);
            }
            wave_reduce_sum_n<4>(e);
            if (lane == 0) {
#pragma unroll
                for (int p = 0; p < PP; p++)
                    ws[WS_RVN + (d * NB + b_) * 4 + p] = sqrtf(e[p]);
            }
        }

        // bf16 frag-major convert
        uint16_t* q2bf = (uint16_t*)(ws + WS_Q2BF);
        size_t bdbase = (size_t)(d * NB + b_) * (S2 * HH);
        int jt = j_ >> 4, jcol = j_ & 15;
        int sg = lane >> 3;
        int khalf = (lane >> 1) & 3;
        int elo = (lane & 1) * 4;
        size_t off = bdbase + ((size_t)(jt * 8 + sg) * 64 + (khalf << 4) + jcol) * 8 + elo;
        uint2 pk;
        pk.x = pk2(v.x, v.y);
        pk.y = pk2(v.z, v.w);
        *reinterpret_cast<uint2*>(q2bf + off) = pk;
    } else {
        int idx = gwid - NQ2;
        int d = idx >> 11;
        int b = (idx >> 7) & 15;
        int i = idx & 127;
        const float* row = q1 + ((size_t)(b * S1 + i)) * FULLH + d * HH;
        float4 v = *reinterpret_cast<const float4*>(row + h0);

        int banks[4] = {2 + d, d, 4 + d, 6 + d};
        float s[17];
        s[0] = dot4(v, v);
#pragma unroll
        for (int t = 0; t < 4; t++) {
#pragma unroll
            for (int p = 0; p < PP; p++) {
                float4 wv = *reinterpret_cast<const float4*>(
                    W + ((size_t)banks[t] * PP + p) * HH + h0);
                float4 tv;
                tv.x = v.x * wv.x; tv.y = v.y * wv.y;
                tv.z = v.z * wv.z; tv.w = v.w * wv.w;
                s[1 + t * 4 + p] = dot4(tv, tv);
            }
        }
        wave_reduce_sum_n<17>(s);
        if (lane == 0) {
            ws[WS_N1 + idx] = sqrtf(s[0]);
#pragma unroll
            for (int p = 0; p < PP; p++)
                ws[WS_N1W + (size_t)idx * PP + p] = sqrtf(s[1 + p]);
#pragma unroll
            for (int t = 0; t < 3; t++)
#pragma unroll
                for (int p = 0; p < PP; p++)
                    ws[WS_N1X + (size_t)idx * 12 + t * 4 + p] = sqrtf(s[5 + t * 4 + p]);
        }
    }
}

// MFMA S-phase: 1 wave per block; block = (d, b, itile of 16 rows, jquarter of 48 cols).
__global__ __launch_bounds__(64) void s_mfma_kernel(const float* __restrict__ q1,
                                                    const float* __restrict__ W,
                                                    float* __restrict__ ws) {
    __shared__ short lA[5 * 2 * 64 * 8];
    __shared__ short lB[6 * 64 * 8];

    int bid = blockIdx.x;
    int jq = bid & 3;
    int itile = (bid >> 2) & 7;
    int b = (bid >> 5) & 15;
    int d = bid >> 9;
    int t = threadIdx.x;

    const uint16_t* q2bf = (const uint16_t*)(ws + WS_Q2BF) + (size_t)(d * NB + b) * (S2 * HH);

    f32x4 acc[5][3];
#pragma unroll
    for (int v = 0; v < 5; v++)
#pragma unroll
        for (int jt_i = 0; jt_i < 3; jt_i++) acc[v][jt_i] = (f32x4){0.f, 0.f, 0.f, 0.f};

    int ar = t >> 2;
    int ak0 = (t & 3) << 4;
    int a_sloc = ak0 >> 5;
    int a_kh = (ak0 >> 3) & 3;
    const float* q1row = q1 + ((size_t)(b * S1 + itile * 16 + ar)) * FULLH + d * HH;

    for (int kc = 0; kc < 4; kc++) {
#pragma unroll
        for (int ci = 0; ci < 6; ci++) {
            int jt = jq * 3 + (ci >> 1);
            int sg = kc * 2 + (ci & 1);
            uint4 src = *reinterpret_cast<const uint4*>(
                q2bf + ((size_t)(jt * 8 + sg) * 64 + t) * 8);
            *reinterpret_cast<uint4*>(&lB[(ci * 64 + t) * 8]) = src;
        }
        {
            int kg = kc * 64 + ak0;
            float4 x0 = *reinterpret_cast<const float4*>(q1row + kg);
            float4 x1 = *reinterpret_cast<const float4*>(q1row + kg + 4);
            float4 x2 = *reinterpret_cast<const float4*>(q1row + kg + 8);
            float4 x3 = *reinterpret_cast<const float4*>(q1row + kg + 12);
#pragma unroll
            for (int v = 0; v < 5; v++) {
                float4 y0 = x0, y1 = x1, y2 = x2, y3 = x3;
                if (v > 0) {
                    const float* wrow = W + ((size_t)((2 + d) * PP + (v - 1))) * HH + kg;
                    float4 w0 = *reinterpret_cast<const float4*>(wrow);
                    float4 w1 = *reinterpret_cast<const float4*>(wrow + 4);
                    float4 w2 = *reinterpret_cast<const float4*>(wrow + 8);
                    float4 w3 = *reinterpret_cast<const float4*>(wrow + 12);
                    y0.x *= w0.x * w0.x; y0.y *= w0.y * w0.y; y0.z *= w0.z * w0.z; y0.w *= w0.w * w0.w;
                    y1.x *= w1.x * w1.x; y1.y *= w1.y * w1.y; y1.z *= w1.z * w1.z; y1.w *= w1.w * w1.w;
                    y2.x *= w2.x * w2.x; y2.y *= w2.y * w2.y; y2.z *= w2.z * w2.z; y2.w *= w2.w * w2.w;
                    y3.x *= w3.x * w3.x; y3.y *= w3.y * w3.y; y3.z *= w3.z * w3.z; y3.w *= w3.w * w3.w;
                }
                uint4 c0, c1;
                c0.x = pk2(y0.x, y0.y); c0.y = pk2(y0.z, y0.w);
                c0.z = pk2(y1.x, y1.y); c0.w = pk2(y1.z, y1.w);
                c1.x = pk2(y2.x, y2.y); c1.y = pk2(y2.z, y2.w);
                c1.z = pk2(y3.x, y3.y); c1.w = pk2(y3.z, y3.w);
                int base = ((v * 2 + a_sloc) * 64 + (a_kh << 4) + ar) * 8;
                *reinterpret_cast<uint4*>(&lA[base]) = c0;
                *reinterpret_cast<uint4*>(&lA[base + 128]) = c1;
            }
        }
        __syncthreads();
#pragma unroll
        for (int sl = 0; sl < 2; sl++) {
            short8 a[5];
#pragma unroll
            for (int v = 0; v < 5; v++)
                a[v] = *reinterpret_cast<const short8*>(&lA[((v * 2 + sl) * 64 + t) * 8]);
#pragma unroll
            for (int jt_i = 0; jt_i < 3; jt_i++) {
                short8 bf = *reinterpret_cast<const short8*>(&lB[((jt_i * 2 + sl) * 64 + t) * 8]);
#pragma unroll
                for (int v = 0; v < 5; v++)
                    acc[v][jt_i] = __builtin_amdgcn_mfma_f32_16x16x32_bf16(a[v], bf, acc[v][jt_i], 0, 0, 0);
            }
        }
        __syncthreads();
    }

    int lhi = t >> 4;
    int lcol = t & 15;
    int nbase = d * (NB * S2) + b * S2;
    int q1b = d * (NB * S1) + b * S1 + itile * 16 + lhi * 4;
    int iloc = itile * 16 + lhi * 4;
    float* attT = ws + WS_ATT + (size_t)(d * NB + b) * S2 * S1;

    float n1[4], n1wc[4][4];
#pragma unroll
    for (int rr = 0; rr < 4; rr++) {
        n1[rr] = ws[WS_N1 + q1b + rr];
#pragma unroll
        for (int p = 0; p < 4; p++)
            n1wc[rr][p] = fmaxf(ws[WS_N1W + (size_t)(q1b + rr) * 4 + p], EPSV);
    }

    float satt_acc[4] = {0.f, 0.f, 0.f, 0.f};
    float mc_acc[4][4];
#pragma unroll
    for (int p = 0; p < 4; p++)
#pragma unroll
        for (int rr = 0; rr < 4; rr++) mc_acc[p][rr] = -INFINITY;

#pragma unroll
    for (int jt_i = 0; jt_i < 3; jt_i++) {
        int j = (jq * 3 + jt_i) * 16 + lcol;
        float n2 = ws[WS_N2 + nbase + j];
        float4 av;
        float avv[4];
#pragma unroll
        for (int rr = 0; rr < 4; rr++) {
            float den = n1[rr] * n2;
            avv[rr] = acc[0][jt_i][rr] / (den > EPSV ? den : EPSV);
            satt_acc[rr] += avv[rr];
        }
        av.x = avv[0]; av.y = avv[1]; av.z = avv[2]; av.w = avv[3];
        *reinterpret_cast<float4*>(&attT[(size_t)j * S1 + iloc]) = av;  // transposed
#pragma unroll
        for (int p = 0; p < 4; p++) {
            float n2wv = fmaxf(ws[WS_N2W + (size_t)(nbase + j) * 4 + p], EPSV);
#pragma unroll
            for (int rr = 0; rr < 4; rr++) {
                float cosv = acc[p + 1][jt_i][rr] / (n1wc[rr][p] * n2wv);
                mc_acc[p][rr] = fmaxf(mc_acc[p][rr], cosv);
            }
        }
    }

#pragma unroll
    for (int m = 1; m < 16; m <<= 1) {
#pragma unroll
        for (int rr = 0; rr < 4; rr++) satt_acc[rr] += __shfl_xor(satt_acc[rr], m, 64);
#pragma unroll
        for (int p = 0; p < 4; p++)
#pragma unroll
            for (int rr = 0; rr < 4; rr++)
                mc_acc[p][rr] = fmaxf(mc_acc[p][rr], __shfl_xor(mc_acc[p][rr], m, 64));
    }
    if (lcol == 0) {
#pragma unroll
        for (int rr = 0; rr < 4; rr++) {
            ws[WS_SATT + jq * 4096 + q1b + rr] = satt_acc[rr];
#pragma unroll
            for (int p = 0; p < 4; p++)
                ws[WS_MC + (size_t)(jq * 4096 + q1b + rr) * 4 + p] = mc_acc[p][rr];
        }
    }
}

// Apply v4: block = (d, b, itile of 4 i's), 4 waves; wave w streams j in
// [48w, 48w+48) for all 4 i's; one LDS combine; wave w finishes i=i0+w.
// 1024 blocks -> 4 blocks/CU -> 4 waves/SIMD.
__global__ __launch_bounds__(256, 4) void apply_kernel(const float* __restrict__ q1,
                                                       const float* __restrict__ q2,
                                                       const float* __restrict__ W,
                                                       const float* __restrict__ ws,
                                                       float* __restrict__ out) {
    __shared__ float lds_m[4][4][HH];   // [wave][i][h] mean partials, 16 KB
    __shared__ float lds_x[4][4][HH];   // [wave][i][h] max partials,  16 KB

    int bid = blockIdx.x;
    int xcd = bid & 7;
    int rest = bid >> 3;             // 0..127
    int db = xcd + 8 * (rest & 3);   // 0..31 pinned to one XCD
    int itile = rest >> 2;           // 0..31
    int d = db >> 4;
    int b = db & 15;

    int tid = threadIdx.x;
    int w = tid >> 6;
    int lane = tid & 63;
    int h0 = lane * 4;
    int i0 = itile * 4;

    const float* q2b = q2 + (size_t)b * S2 * FULLH + d * HH;
    const float* attT = ws + WS_ATT + (size_t)db * S2 * S1 + i0;

    f32x4 macc[4], mx[4];
#pragma unroll
    for (int ii = 0; ii < 4; ii++) {
        macc[ii] = (f32x4){0.f, 0.f, 0.f, 0.f};
        mx[ii] = (f32x4){-INFINITY, -INFINITY, -INFINITY, -INFINITY};
    }

    int j0 = w * 48;
#pragma unroll 4
    for (int jj = 0; jj < 48; jj++) {
        int j = j0 + jj;
        f32x4 qv = *reinterpret_cast<const f32x4*>(q2b + (size_t)j * FULLH + h0);
        f32x4 a4 = *reinterpret_cast<const f32x4*>(attT + (size_t)j * S1);
        float av[4] = {a4.x, a4.y, a4.z, a4.w};
#pragma unroll
        for (int ii = 0; ii < 4; ii++) {
            f32x4 ab = (f32x4){av[ii], av[ii], av[ii], av[ii]};
            macc[ii] = __builtin_elementwise_fma(ab, qv, macc[ii]);
            mx[ii] = __builtin_elementwise_max(mx[ii], ab * qv);
        }
    }

#pragma unroll
    for (int ii = 0; ii < 4; ii++) {
        *reinterpret_cast<f32x4*>(&lds_m[w][ii][h0]) = macc[ii];
        *reinterpret_cast<f32x4*>(&lds_x[w][ii][h0]) = mx[ii];
    }
    __syncthreads();

    // wave w finishes i = i0 + w
    f32x4 cm = (f32x4){0.f, 0.f, 0.f, 0.f};
    f32x4 cx = (f32x4){-INFINITY, -INFINITY, -INFINITY, -INFINITY};
#pragma unroll
    for (int wp = 0; wp < 4; wp++) {
        cm += *reinterpret_cast<const f32x4*>(&lds_m[wp][w][h0]);
        cx = __builtin_elementwise_max(cx, *reinterpret_cast<const f32x4*>(&lds_x[wp][w][h0]));
    }

    int i = i0 + w;
    int qi = d * (NB * S1) + b * S1 + i;
    size_t obase = ((size_t)(b * S1 + i)) * 32;

    float satt = ws[WS_SATT + 0 * 4096 + qi] + ws[WS_SATT + 1 * 4096 + qi] +
                 ws[WS_SATT + 2 * 4096 + qi] + ws[WS_SATT + 3 * 4096 + qi];
    float sden = satt > EPSV ? satt : EPSV;

    if (lane < 4) {
        float m = -INFINITY;
#pragma unroll
        for (int jq = 0; jq < 4; jq++)
            m = fmaxf(m, ws[WS_MC + (size_t)(jq * 4096 + qi) * 4 + lane]);
        out[obase + 8 + 4 * d + lane] = m;
    }

    f32x4 mean = cm * (1.0f / sden);
    f32x4 rv = *reinterpret_cast<const f32x4*>(
        q2b + (d == 0 ? (size_t)(S2 - 1) * FULLH : (size_t)0) + h0);
    f32x4 q1v = *reinterpret_cast<const f32x4*>(
        q1 + ((size_t)(b * S1 + i)) * FULLH + d * HH + h0);

    f32x4 q1rv = q1v * rv, q1me = q1v * mean, me2 = mean * mean;
    f32x4 q1mx = q1v * cx, mx2 = cx * cx;

    // s[p*5 + {0:full-num, 1:att-num, 2:mean2, 3:max-num, 4:mx2}]
    float s[20];
#pragma unroll
    for (int p = 0; p < 4; p++) {
        f32x4 wf = *reinterpret_cast<const f32x4*>(W + ((size_t)d * PP + p) * HH + h0);
        f32x4 wa = *reinterpret_cast<const f32x4*>(W + ((size_t)(4 + d) * PP + p) * HH + h0);
        f32x4 wm = *reinterpret_cast<const f32x4*>(W + ((size_t)(6 + d) * PP + p) * HH + h0);
        f32x4 w2f = wf * wf, w2a = wa * wa, w2m = wm * wm;
        s[p * 5 + 0] = vdot4(q1rv, w2f);
        s[p * 5 + 1] = vdot4(q1me, w2a);
        s[p * 5 + 2] = vdot4(me2, w2a);
        s[p * 5 + 3] = vdot4(q1mx, w2m);
        s[p * 5 + 4] = vdot4(mx2, w2m);
    }
    wave_reduce_sum_n<20>(s);

    if (lane == 0) {
        const float* nx = ws + WS_N1X + (size_t)qi * 12;
#pragma unroll
        for (int p = 0; p < 4; p++) {
            float nf = fmaxf(nx[p], EPSV);
            float na = fmaxf(nx[4 + p], EPSV);
            float nm = fmaxf(nx[8 + p], EPSV);
            float rvn = fmaxf(ws[WS_RVN + (d * NB + b) * 4 + p], EPSV);
            const float* sp = s + p * 5;
            out[obase + 0 + 4 * d + p] = sp[0] / (nf * rvn);
            out[obase + 16 + 4 * d + p] = sp[1] / (na * fmaxf(sqrtf(sp[2]), EPSV));
            out[obase + 24 + 4 * d + p] = sp[3] / (nm * fmaxf(sqrtf(sp[4]), EPSV));
        }
    }
}

extern "C" void kernel_launch(void* const* d_in, const int* in_sizes, int n_in,
                              void* d_out, int out_size, void* d_ws, size_t ws_size,
                              hipStream_t stream) {
    const float* q1 = (const float*)d_in[0];
    const float* q2 = (const float*)d_in[1];
    const float* W = (const float*)d_in[2];
    float* out = (float*)d_out;
    float* ws = (float*)d_ws;

    int nrows = 2 * NB * S2 + 2 * NB * S1;             // 10240 waves
    int nblocks_norm = (nrows * 64 + 255) / 256;       // 2560
    norms_kernel<<<dim3(nblocks_norm), dim3(256), 0, stream>>>(q1, q2, W, ws);

    s_mfma_kernel<<<dim3(2 * NB * 8 * 4), dim3(64), 0, stream>>>(q1, W, ws);

    apply_kernel<<<dim3(1024), dim3(256), 0, stream>>>(q1, q2, W, ws, out);
}